// Round 1
// baseline (165.508 us; speedup 1.0000x reference)
//
#include <hip/hip_runtime.h>
#include <stdint.h>

typedef float  f32x4  __attribute__((ext_vector_type(4)));
typedef short  s16x8  __attribute__((ext_vector_type(8)));
typedef unsigned short u16;
typedef unsigned short u16x4 __attribute__((ext_vector_type(4)));
typedef unsigned short u16x8 __attribute__((ext_vector_type(8)));

#define DEVI __device__ __forceinline__

DEVI u16 f2bf(float x) {
  uint32_t u = __float_as_uint(x);
  u += 0x7fffu + ((u >> 16) & 1u);   // RNE to bf16
  return (u16)(u >> 16);
}
DEVI float bf2f(u16 h) { return __uint_as_float(((uint32_t)h) << 16); }
DEVI float sigm(float x) { return 1.0f / (1.0f + __expf(-x)); }

template<int HEAD> DEVI float anchW(int a) {
  if constexpr (HEAD == 0) return a == 0 ? 116.f/416.f : (a == 1 ? 156.f/416.f : 373.f/416.f);
  else if constexpr (HEAD == 1) return a == 0 ? 30.f/416.f : (a == 1 ? 62.f/416.f : 59.f/416.f);
  else return a == 0 ? 10.f/416.f : (a == 1 ? 16.f/416.f : 33.f/416.f);
}
template<int HEAD> DEVI float anchH(int a) {
  if constexpr (HEAD == 0) return a == 0 ? 90.f/416.f : (a == 1 ? 198.f/416.f : 326.f/416.f);
  else if constexpr (HEAD == 1) return a == 0 ? 61.f/416.f : (a == 1 ? 45.f/416.f : 119.f/416.f);
  else return a == 0 ? 13.f/416.f : (a == 1 ? 30.f/416.f : 23.f/416.f);
}

// Block tile: 256 (channels, padded from 255) x 64 (spatial), BK=32.
// 8 waves: wave grid 4(M) x 2(N), wave tile 64x32, 16x16x32 bf16 MFMA frags.
// bf16x2 split, 3 MFMA passes per frag -> ~fp32 accuracy.
template<int K, int WD, int HEAD>
DEVI void head_block(const float* __restrict__ F, const float* __restrict__ Wt,
                     const float* __restrict__ bias, float* __restrict__ out,
                     int bidx, char* smem)
{
  constexpr int S  = WD * WD;
  constexpr int NT = (S + 63) / 64;
  constexpr int RP = 40;            // padded LDS row, elements (80 B -> ~2-way b128)

  const int b  = bidx / NT;
  const int s0 = (bidx - b * NT) * 64;

  const int tid  = (int)threadIdx.x;
  const int lane = tid & 63;
  const int wv   = tid >> 6;        // 0..7
  const int wm   = wv >> 1;         // 0..3 -> channel rows wm*64
  const int wn   = wv & 1;          // 0..1 -> spatial cols wn*32

  u16* As_hi = (u16*)(smem);                 // [256][40]
  u16* As_lo = (u16*)(smem + 20480);
  u16* Bs_hi = (u16*)(smem + 40960);         // [64][40]
  u16* Bs_lo = (u16*)(smem + 46080);

  const float* Fb = F + (size_t)b * K * S;

  f32x4 acc[4][2];
  #pragma unroll
  for (int i = 0; i < 4; ++i)
    #pragma unroll
    for (int j = 0; j < 2; ++j)
      #pragma unroll
      for (int r = 0; r < 4; ++r) acc[i][j][r] = 0.f;

  // staging index precompute
  const int ar  = tid >> 1;            // A row 0..255
  const int akh = (tid & 1) << 4;      // k half: 0 | 16
  const int bsl = tid & 63;            // B spatial lane 0..63
  const int bkg = tid >> 6;            // B k group 0..7 (4 k each)
  const int bs  = (s0 + bsl < S) ? (s0 + bsl) : (S - 1);

  for (int k0 = 0; k0 < K; k0 += 32) {
    // ---- stage A (weights 256x32 fp32 -> bf16 hi/lo) ----
    #pragma unroll
    for (int h = 0; h < 2; ++h) {
      float x[8];
      if (ar < 255) {
        const f32x4* src = (const f32x4*)(Wt + (size_t)ar * K + k0 + akh + h * 8);
        f32x4 v0 = src[0], v1 = src[1];
        x[0]=v0[0]; x[1]=v0[1]; x[2]=v0[2]; x[3]=v0[3];
        x[4]=v1[0]; x[5]=v1[1]; x[6]=v1[2]; x[7]=v1[3];
      } else {
        #pragma unroll
        for (int i = 0; i < 8; ++i) x[i] = 0.f;
      }
      u16x8 hv, lv;
      #pragma unroll
      for (int i = 0; i < 8; ++i) {
        u16 hi = f2bf(x[i]);
        hv[i] = hi;
        lv[i] = f2bf(x[i] - bf2f(hi));
      }
      const int off = ar * RP + akh + h * 8;
      *(u16x8*)(As_hi + off) = hv;
      *(u16x8*)(As_lo + off) = lv;
    }
    // ---- stage B (features 32x64 fp32 -> bf16 hi/lo, transposed to [n][k]) ----
    {
      const float* fp = Fb + (size_t)(k0 + bkg * 4) * S + bs;
      u16x4 hv, lv;
      #pragma unroll
      for (int j = 0; j < 4; ++j) {
        float x = fp[(size_t)j * S];
        u16 hi = f2bf(x);
        hv[j] = hi;
        lv[j] = f2bf(x - bf2f(hi));
      }
      const int off = bsl * RP + bkg * 4;
      *(u16x4*)(Bs_hi + off) = hv;
      *(u16x4*)(Bs_lo + off) = lv;
    }
    __syncthreads();
    // ---- MFMA: 4m x 2n frags, 3 passes each ----
    {
      const int g16  = (lane >> 4) << 3;   // k element offset 0/8/16/24
      const int ridx = lane & 15;
      s16x8 Ahi[4], Alo[4], Bhi[2], Blo[2];
      #pragma unroll
      for (int mf = 0; mf < 4; ++mf) {
        const int off = (wm * 64 + mf * 16 + ridx) * RP + g16;
        Ahi[mf] = *(const s16x8*)(As_hi + off);
        Alo[mf] = *(const s16x8*)(As_lo + off);
      }
      #pragma unroll
      for (int nf = 0; nf < 2; ++nf) {
        const int off = (wn * 32 + nf * 16 + ridx) * RP + g16;
        Bhi[nf] = *(const s16x8*)(Bs_hi + off);
        Blo[nf] = *(const s16x8*)(Bs_lo + off);
      }
      #pragma unroll
      for (int mf = 0; mf < 4; ++mf)
        #pragma unroll
        for (int nf = 0; nf < 2; ++nf) {
          acc[mf][nf] = __builtin_amdgcn_mfma_f32_16x16x32_bf16(Ahi[mf], Bhi[nf], acc[mf][nf], 0, 0, 0);
          acc[mf][nf] = __builtin_amdgcn_mfma_f32_16x16x32_bf16(Ahi[mf], Blo[nf], acc[mf][nf], 0, 0, 0);
          acc[mf][nf] = __builtin_amdgcn_mfma_f32_16x16x32_bf16(Alo[mf], Bhi[nf], acc[mf][nf], 0, 0, 0);
        }
    }
    __syncthreads();
  }

  // ---- epilogue: decode in-register, transpose via LDS, coalesced store ----
  float* ot = (float*)smem;   // [3][64][85] = 16320 floats (reuses staging LDS)
  #pragma unroll
  for (int mf = 0; mf < 4; ++mf) {
    const int mbase = wm * 64 + mf * 16 + ((lane >> 4) << 2);
    #pragma unroll
    for (int nf = 0; nf < 2; ++nf) {
      const int sl = wn * 32 + nf * 16 + (lane & 15);
      const int s  = s0 + sl;
      const int hh = s / WD;
      const int ww = s - hh * WD;
      #pragma unroll
      for (int r = 0; r < 4; ++r) {
        const int m = mbase + r;
        if (m > 254) continue;
        const float p    = acc[mf][nf][r] + bias[m];
        const int   a    = (m * 772) >> 16;   // m/85, exact for m<=254
        const int   attr = m - 85 * a;
        float val;
        if      (attr == 0) val = ((float)ww + sigm(p)) * (1.0f / WD);
        else if (attr == 1) val = ((float)hh + sigm(p)) * (1.0f / WD);
        else if (attr == 2) val = __expf(p) * anchW<HEAD>(a);
        else if (attr == 3) val = __expf(p) * anchH<HEAD>(a);
        else                val = sigm(p);
        ot[(a * 64 + sl) * 85 + attr] = val;
      }
    }
  }
  __syncthreads();
  const int vs = (S - s0) < 64 ? (S - s0) : 64;
  for (int i = tid; i < 3 * 64 * 85; i += 512) {
    const int a   = i / 5440;
    const int rem = i - a * 5440;
    const int sl  = rem / 85;
    if (sl < vs)
      out[((size_t)(b * 3 + a) * S + s0) * 85 + rem] = ot[i];
  }
}

__global__ __launch_bounds__(512, 4)
void yolo_fused(const float* __restrict__ f13, const float* __restrict__ f26,
                const float* __restrict__ f52,
                const float* __restrict__ W13, const float* __restrict__ b13,
                const float* __restrict__ W26, const float* __restrict__ b26,
                const float* __restrict__ W52, const float* __restrict__ b52,
                float* __restrict__ out)
{
  __shared__ __attribute__((aligned(16))) char smem[65280];
  const int blk = (int)blockIdx.x;
  float* out13 = out;
  float* out26 = out + 1379040;          // 32*507*85
  float* out52 = out + 6895200;          // + 32*2028*85
  if (blk < 96)        head_block<1024, 13, 0>(f13, W13, b13, out13, blk,       smem);
  else if (blk < 448)  head_block< 512, 26, 1>(f26, W26, b26, out26, blk - 96,  smem);
  else                 head_block< 256, 52, 2>(f52, W52, b52, out52, blk - 448, smem);
}

extern "C" void kernel_launch(void* const* d_in, const int* in_sizes, int n_in,
                              void* d_out, int out_size, void* d_ws, size_t ws_size,
                              hipStream_t stream) {
  (void)in_sizes; (void)n_in; (void)d_ws; (void)ws_size; (void)out_size;
  const float* f13 = (const float*)d_in[0];
  const float* f26 = (const float*)d_in[1];
  const float* f52 = (const float*)d_in[2];
  const float* W13 = (const float*)d_in[3];
  const float* b13 = (const float*)d_in[4];
  const float* W26 = (const float*)d_in[5];
  const float* b26 = (const float*)d_in[6];
  const float* W52 = (const float*)d_in[7];
  const float* b52 = (const float*)d_in[8];
  // 96 + 352 + 1376 = 1824 blocks; longest-K (head13) blocks dispatched first.
  yolo_fused<<<dim3(1824), dim3(512), 0, stream>>>(
      f13, f26, f52, W13, b13, W26, b26, W52, b52, (float*)d_out);
}